// Round 9
// baseline (72.712 us; speedup 1.0000x reference)
//
#include <hip/hip_runtime.h>

typedef _Float16 half8 __attribute__((ext_vector_type(8)));
typedef float f32x4 __attribute__((ext_vector_type(4)));
typedef float f32x16 __attribute__((ext_vector_type(16)));
typedef unsigned int u32x4 __attribute__((ext_vector_type(4)));

#define DD 128

// Workspace layout (32x32x16 fragment order):
//   FRAG: nch32 records of 16384 B. Record c, k-step q (0..7), hl in {0,1},
//         lane l at offset q*2048 + hl*1024 + l*16: 8 f16 of
//         code n = c*32 + (l&31), k = q*16 + (l>>5)*8 + 0..7.
//         hl=0 -> f16 hi half, hl=1 -> f16 lo half (v - (f16)v).
//   E2NEG (after FRAG): K floats, -||e_n||^2 dedup (computed in double).

__global__ void prep_kernel(const float* __restrict__ embed,
                            char* __restrict__ frag,
                            float* __restrict__ e2neg, int total) {
  int t = blockIdx.x * blockDim.x + threadIdx.x;
  if (t >= total) return;
  int lane = t & 63;
  int sub = (t >> 6) & 15;  // q*2 + hl
  int c = t >> 10;
  int q = sub >> 1;
  int hl = sub & 1;
  int n = c * 32 + (lane & 31);
  int kb = q * 16 + ((lane >> 5) << 3);
  const float* src = embed + (size_t)n * DD + kb;
  _Float16* dst =
      (_Float16*)(frag + (size_t)c * 16384 + q * 2048 + hl * 1024 + lane * 16);
#pragma unroll
  for (int j = 0; j < 8; ++j) {
    float v = src[j];
    _Float16 hi = (_Float16)v;
    dst[j] = hl ? (_Float16)(v - (float)hi) : hi;
  }
  if (sub == 0 && lane < 32) {
    const float* e = embed + (size_t)n * DD;
    double acc = 0.0;
    for (int j = 0; j < DD; ++j) { double v = (double)e[j]; acc += v * v; }
    e2neg[n] = (float)(-acc);
  }
}

// ---------------------------------------------------------------------------
// Main: block = 256 thr (4 waves), block owns 128 rows (wave w: 32 rows).
// 32x32x16 MFMA (full-rate shape, m119: 2495 TF): per 32-code chunk per wave
// 24 MFMAs in 2 chains (hh 8-deep, lo 16-deep). Chunk loop 2x-unrolled with
// DOUBLE-BUFFERED ACCUMULATORS (accA/accB): chunk c's argmax epilogue runs
// while chunk c+1's MFMAs fill the pipe — kills the ~25us WAR/latency stall
// the R7 ablation isolated (epilogue differential). e2 preloaded a phase
// early. B staged once per block into dbuf LDS (R6-proven reg-stage skeleton,
// one barrier per chunk). C/D: col=lane&31, row=(reg&3)+8*(reg>>2)+4*(l>>5).
// ---------------------------------------------------------------------------
__global__ __launch_bounds__(256) void vq_argmin_kernel(
    const float* __restrict__ x, const float* __restrict__ embed,
    const char* __restrict__ wsf, const float* __restrict__ wse2,
    float* __restrict__ out_q, float* __restrict__ out_i, int nch32) {
  const int tid = threadIdx.x;
  const int lane = tid & 63;
  const int w = tid >> 6;
  const int m32 = lane & 31;
  const int h = lane >> 5;
  const int row0 = blockIdx.x * 128 + w * 32;

  __shared__ alignas(16) char lds[2][16384];

  // A fragments: lane holds x[row0+m32][q*16 + h*8 .. +8), f16 hi/lo split.
  half8 ah[8], al[8];
  {
    const float* xrow = x + (size_t)(row0 + m32) * DD;
#pragma unroll
    for (int q = 0; q < 8; ++q) {
      const float* p = xrow + q * 16 + h * 8;
      f32x4 v0 = *(const f32x4*)(p);
      f32x4 v1 = *(const f32x4*)(p + 4);
#pragma unroll
      for (int j = 0; j < 4; ++j) {
        float v = v0[j];
        _Float16 hi = (_Float16)v;
        ah[q][j] = hi;
        al[q][j] = (_Float16)(v - (float)hi);
      }
#pragma unroll
      for (int j = 0; j < 4; ++j) {
        float v = v1[j];
        _Float16 hi = (_Float16)v;
        ah[q][4 + j] = hi;
        al[q][4 + j] = (_Float16)(v - (float)hi);
      }
    }
  }

  float bestv[16];
  int besti[16];
#pragma unroll
  for (int r = 0; r < 16; ++r) {
    bestv[r] = -__builtin_inff();
    besti[r] = 0;
  }

  f32x16 hhA, loA, hhB, loB;
  float neA = 0.f, neB = 0.f;

#define EPI(HH, LO, NE, NB)                                     \
  do {                                                          \
    const int nb_ = (NB);                                       \
    _Pragma("unroll") for (int r = 0; r < 16; ++r) {            \
      float sc = fmaf(2.f, HH[r] + LO[r], NE);                  \
      if (sc > bestv[r]) { bestv[r] = sc; besti[r] = nb_; }     \
    }                                                           \
  } while (0)

#define MFMA_CHUNK(HH, LO, BUF)                                                \
  do {                                                                         \
    _Pragma("unroll") for (int r = 0; r < 16; ++r) { HH[r] = 0.f;              \
                                                     LO[r] = 0.f; }            \
    _Pragma("unroll") for (int q = 0; q < 8; ++q) {                            \
      const char* fb_ = &lds[BUF][q * 2048 + lane * 16];                       \
      half8 bh_ = *(const half8*)(fb_);                                        \
      half8 bl_ = *(const half8*)(fb_ + 1024);                                 \
      HH = __builtin_amdgcn_mfma_f32_32x32x16_f16(ah[q], bh_, HH, 0, 0, 0);    \
      LO = __builtin_amdgcn_mfma_f32_32x32x16_f16(al[q], bh_, LO, 0, 0, 0);    \
      LO = __builtin_amdgcn_mfma_f32_32x32x16_f16(ah[q], bl_, LO, 0, 0, 0);    \
    }                                                                          \
  } while (0)

  // prologue: stage chunk 0 into buf0 (flat copy, 64 B/thread)
  {
    const char* gs = wsf + tid * 16;
    u32x4 s0 = *(const u32x4*)(gs);
    u32x4 s1 = *(const u32x4*)(gs + 4096);
    u32x4 s2 = *(const u32x4*)(gs + 8192);
    u32x4 s3 = *(const u32x4*)(gs + 12288);
    char* lw = &lds[0][tid * 16];
    *(u32x4*)(lw) = s0;
    *(u32x4*)(lw + 4096) = s1;
    *(u32x4*)(lw + 8192) = s2;
    *(u32x4*)(lw + 12288) = s3;
  }
  __syncthreads();

  const int half_iters = nch32 >> 1;
  for (int t = 0; t < half_iters; ++t) {
    const int cA = 2 * t;
    const int cB = 2 * t + 1;

    // ---- A phase: compute chunk cA (buf0); stage chunk cB -> buf1 ----
    u32x4 tA0, tA1, tA2, tA3;
    {
      const char* gs = wsf + (size_t)cB * 16384 + tid * 16;
      tA0 = *(const u32x4*)(gs);
      tA1 = *(const u32x4*)(gs + 4096);
      tA2 = *(const u32x4*)(gs + 8192);
      tA3 = *(const u32x4*)(gs + 12288);
    }
    neA = wse2[cA * 32 + m32];
    MFMA_CHUNK(hhA, loA, 0);
    if (t) EPI(hhB, loB, neB, (cA - 1) * 32 + m32);  // prev B, pipe-covered
    {
      char* lw = &lds[1][tid * 16];
      *(u32x4*)(lw) = tA0;
      *(u32x4*)(lw + 4096) = tA1;
      *(u32x4*)(lw + 8192) = tA2;
      *(u32x4*)(lw + 12288) = tA3;
    }
    __syncthreads();

    // ---- B phase: compute chunk cB (buf1); stage chunk cB+1 -> buf0 ----
    u32x4 tB0, tB1, tB2, tB3;
    const bool preB = (t + 1 < half_iters);
    if (preB) {
      const char* gs = wsf + (size_t)(cB + 1) * 16384 + tid * 16;
      tB0 = *(const u32x4*)(gs);
      tB1 = *(const u32x4*)(gs + 4096);
      tB2 = *(const u32x4*)(gs + 8192);
      tB3 = *(const u32x4*)(gs + 12288);
    }
    neB = wse2[cB * 32 + m32];
    MFMA_CHUNK(hhB, loB, 1);
    EPI(hhA, loA, neA, cA * 32 + m32);  // covered by B-chunk MFMAs
    if (preB) {
      char* lw = &lds[0][tid * 16];
      *(u32x4*)(lw) = tB0;
      *(u32x4*)(lw + 4096) = tB1;
      *(u32x4*)(lw + 8192) = tB2;
      *(u32x4*)(lw + 12288) = tB3;
    }
    __syncthreads();
  }
  EPI(hhB, loB, neB, (nch32 - 1) * 32 + m32);
#undef MFMA_CHUNK
#undef EPI

  // reduce across the 32 lanes (codes) of each half; smaller index on tie
#pragma unroll
  for (int off = 1; off < 32; off <<= 1) {
#pragma unroll
    for (int r = 0; r < 16; ++r) {
      float ov = __shfl_xor(bestv[r], off, 64);
      int oi = __shfl_xor(besti[r], off, 64);
      if (ov > bestv[r] || (ov == bestv[r] && oi < besti[r])) {
        bestv[r] = ov;
        besti[r] = oi;
      }
    }
  }

  // outputs: row = row0 + (r&3) + 8*(r>>2) + 4*h; 32 lanes x f32x4 per row
#pragma unroll
  for (int r = 0; r < 16; ++r) {
    const int row = row0 + (r & 3) + 8 * (r >> 2) + 4 * h;
    const int idx = besti[r];
    if (m32 == 0) out_i[row] = (float)idx;
    const f32x4* src = (const f32x4*)(embed + (size_t)idx * DD) + m32;
    f32x4* dst = (f32x4*)(out_q + (size_t)row * DD) + m32;
    *dst = *src;
  }
}

// ---------------------------------------------------------------------------
// Fallback: exact double-precision distance, thread per row.
// ---------------------------------------------------------------------------
__global__ void vq_fallback_kernel(const float* __restrict__ x,
                                   const float* __restrict__ embed,
                                   float* __restrict__ out_q,
                                   float* __restrict__ out_i, int N, int K) {
  int row = blockIdx.x * blockDim.x + threadIdx.x;
  if (row >= N) return;
  const float* xr = x + (size_t)row * DD;
  float xv[DD];
  for (int j = 0; j < DD; ++j) xv[j] = xr[j];
  double best = -1e300;
  int bi = 0;
  for (int k = 0; k < K; ++k) {
    const float* e = embed + (size_t)k * DD;
    double acc = 0.0;
    for (int j = 0; j < DD; ++j) {
      double d = (double)xv[j] - (double)e[j];
      acc += d * d;
    }
    double sc = -acc;
    if (sc > best) { best = sc; bi = k; }
  }
  out_i[row] = (float)bi;
  for (int j = 0; j < DD; ++j)
    out_q[(size_t)row * DD + j] = embed[(size_t)bi * DD + j];
}

extern "C" void kernel_launch(void* const* d_in, const int* in_sizes, int n_in,
                              void* d_out, int out_size, void* d_ws,
                              size_t ws_size, hipStream_t stream) {
  const float* x = (const float*)d_in[0];
  const float* embed = (const float*)d_in[1];
  const int N = in_sizes[0] / DD;  // 65536 rows
  const int K = in_sizes[1] / DD;  // 1024 codes
  float* out_q = (float*)d_out;
  float* out_i = out_q + (size_t)N * DD;

  const int nch32 = K / 32;
  const size_t frag_bytes = (size_t)nch32 * 16384;
  const size_t e2_bytes = (size_t)K * 4;
  const size_t need = frag_bytes + e2_bytes;

  if (ws_size < need || (N % 128) != 0 || (K % 32) != 0 || (nch32 % 2) != 0) {
    vq_fallback_kernel<<<(N + 255) / 256, 256, 0, stream>>>(x, embed, out_q,
                                                            out_i, N, K);
    return;
  }

  char* wsf = (char*)d_ws;
  float* wse2 = (float*)(wsf + frag_bytes);

  const int total = nch32 * 16 * 64;
  prep_kernel<<<(total + 255) / 256, 256, 0, stream>>>(embed, wsf, wse2,
                                                       total);
  vq_argmin_kernel<<<N / 128, 256, 0, stream>>>(x, embed, wsf, wse2, out_q,
                                                out_i, nch32);
}